// Round 1
// baseline (341.883 us; speedup 1.0000x reference)
//
#include <hip/hip_runtime.h>

typedef unsigned short u16;
typedef __attribute__((ext_vector_type(4))) float f32x4;
typedef __attribute__((ext_vector_type(8))) short s16x8;

#define DEV __device__ __forceinline__

DEV u16 bf16_rne(float f) {
    unsigned u = __builtin_bit_cast(unsigned, f);
    u += 0x7fffu + ((u >> 16) & 1u);
    return (u16)(u >> 16);
}
DEV float bf2f(u16 h) {
    unsigned u = ((unsigned)h) << 16;
    return __builtin_bit_cast(float, u);
}
DEV void gload_lds16(const void* g, void* l) {
    __builtin_amdgcn_global_load_lds((const __attribute__((address_space(1))) void*)g,
                                     (__attribute__((address_space(3))) void*)l, 16, 0, 0);
}

// ---------------- f32 -> bf16 convert (vectorized x4) ----------------
__global__ __launch_bounds__(256)
void cvt_bf16(const float* __restrict__ in, u16* __restrict__ out, int n4) {
    int i = blockIdx.x * 256 + threadIdx.x;
    if (i >= n4) return;
    f32x4 v = ((const f32x4*)in)[i];
    unsigned long long o =  (unsigned long long)bf16_rne(v[0])
                         | ((unsigned long long)bf16_rne(v[1]) << 16)
                         | ((unsigned long long)bf16_rne(v[2]) << 32)
                         | ((unsigned long long)bf16_rne(v[3]) << 48);
    ((unsigned long long*)out)[i] = o;
}

// ---------------- bf16 GEMM, C = A(MxK) * B(NxK)^T + bias ----------------
// 128x128 tile, BK=64, 256 threads (4 waves, 2x2), mfma 16x16x32 bf16.
template<bool BIAS, bool OUT_BF16>
__global__ __launch_bounds__(256)
void gemm_bt(const u16* __restrict__ A, const u16* __restrict__ B,
             const float* __restrict__ bias, void* __restrict__ Cout,
             int M, int N, int K) {
    __shared__ u16 As[128 * 64];
    __shared__ u16 Bs[128 * 64];
    const int tid = threadIdx.x;
    const int w = tid >> 6, l = tid & 63;
    const int nbn = N >> 7;
    const int bm = blockIdx.x / nbn;
    const int bn = blockIdx.x % nbn;
    const int wr = w >> 1, wc = w & 1;
    const int lr = l & 15, lg = l >> 4;
    const int rowsel = l >> 3, chunk = l & 7;

    f32x4 acc[4][4] = {};

    const u16* Abase = A + (size_t)(bm * 128 + w * 32) * K;
    const u16* Bbase = B + (size_t)(bn * 128 + w * 32) * K;
    u16* AsW = As + (w * 32) * 64;
    u16* BsW = Bs + (w * 32) * 64;

    for (int k0 = 0; k0 < K; k0 += 64) {
        __syncthreads();  // previous tile's reads complete
        #pragma unroll
        for (int i = 0; i < 4; ++i) {
            gload_lds16(Abase + (size_t)(i * 8 + rowsel) * K + k0 + chunk * 8, AsW + i * 8 * 64);
            gload_lds16(Bbase + (size_t)(i * 8 + rowsel) * K + k0 + chunk * 8, BsW + i * 8 * 64);
        }
        __syncthreads();  // staging complete (drains vmcnt)
        #pragma unroll
        for (int ks = 0; ks < 2; ++ks) {
            s16x8 af[4], bfr[4];
            #pragma unroll
            for (int mi = 0; mi < 4; ++mi)
                af[mi] = *(const s16x8*)(As + (wr * 64 + mi * 16 + lr) * 64 + ks * 32 + lg * 8);
            #pragma unroll
            for (int ni = 0; ni < 4; ++ni)
                bfr[ni] = *(const s16x8*)(Bs + (wc * 64 + ni * 16 + lr) * 64 + ks * 32 + lg * 8);
            #pragma unroll
            for (int mi = 0; mi < 4; ++mi)
                #pragma unroll
                for (int ni = 0; ni < 4; ++ni)
                    acc[mi][ni] = __builtin_amdgcn_mfma_f32_16x16x32_bf16(af[mi], bfr[ni], acc[mi][ni], 0, 0, 0);
        }
    }

    const int row0 = bm * 128 + wr * 64;
    const int col0 = bn * 128 + wc * 64;
    #pragma unroll
    for (int ni = 0; ni < 4; ++ni) {
        const int col = col0 + ni * 16 + lr;
        const float bv = BIAS ? bias[col] : 0.0f;
        #pragma unroll
        for (int mi = 0; mi < 4; ++mi) {
            #pragma unroll
            for (int r = 0; r < 4; ++r) {
                const int row = row0 + mi * 16 + lg * 4 + r;  // C/D: col=lane&15, row=(lane>>4)*4+reg
                const float v = acc[mi][ni][r] + bv;
                if (OUT_BF16) ((u16*)Cout)[(size_t)row * N + col] = bf16_rne(v);
                else          ((float*)Cout)[(size_t)row * N + col] = v;
            }
        }
    }
}

// ---------------- RoPE in-place on bf16, pairs (d, d+64) per 128-head ----------------
template<int NHEADS, int ROWSTRIDE>
__global__ __launch_bounds__(256)
void rope_kernel(u16* __restrict__ t, const float* __restrict__ cosb,
                 const float* __restrict__ sinb, float scale) {
    const int i = blockIdx.x * 256 + threadIdx.x;  // over 4096*NHEADS*64, exact
    const int d = i & 63;
    const int h = (i >> 6) % NHEADS;
    const int bs = (i >> 6) / NHEADS;   // b*2048 + s
    const int srow = bs & 2047;         // s
    const size_t base = (size_t)bs * ROWSTRIDE + h * 128;
    const float c0 = cosb[srow * 128 + d],      s0 = sinb[srow * 128 + d];
    const float c1 = cosb[srow * 128 + d + 64], s1 = sinb[srow * 128 + d + 64];
    const float t0 = bf2f(t[base + d]);
    const float t1 = bf2f(t[base + d + 64]);
    t[base + d]      = bf16_rne((t0 * c0 - t1 * s0) * scale);
    t[base + d + 64] = bf16_rne((t1 * c1 + t0 * s1) * scale);
}

// ---------------- causal GQA flash attention ----------------
// grid (16, 32): x = q-tile (128 rows), y = b*16 + h. 4 waves x 32 q-rows.
__global__ __launch_bounds__(256, 2)
void attn_fwd(const u16* __restrict__ Q, const u16* __restrict__ KV, u16* __restrict__ O) {
    __shared__ u16 lds[25600];          // 51200 B
    u16* Ks = lds;                      // [64][128] bf16, XOR-swizzled rows
    u16* Vs = lds + 8192;               // [128][64] V^T, XOR-swizzled rows
    u16* Ps = lds + 16384;              // per-wave [32][72] (pad 8 kills conflicts)

    const int tid = threadIdx.x, w = tid >> 6, l = tid & 63;
    const int lr = l & 15, lg = l >> 4;
    const int qb = blockIdx.x;
    const int bh = blockIdx.y;
    const int b = bh >> 4, h = bh & 15;
    const int kvh = h >> 3;             // rep = 8
    const int q0 = qb * 128;

    // ---- stage Q tile [128][128] via gload_lds into (reused) lds, read A-frags
    {
        const u16* Qg = Q + ((size_t)(b * 2048 + q0 + w * 32) * 2048 + h * 128);
        #pragma unroll
        for (int i = 0; i < 8; ++i)
            gload_lds16(Qg + (size_t)(i * 4 + lg) * 2048 + lr * 8, lds + (w * 32 + i * 4) * 128);
    }
    __syncthreads();
    s16x8 qf[2][4];
    #pragma unroll
    for (int mf = 0; mf < 2; ++mf)
        #pragma unroll
        for (int ks = 0; ks < 4; ++ks)
            qf[mf][ks] = *(const s16x8*)(lds + (w * 32 + mf * 16 + lr) * 128 + ks * 32 + lg * 8);
    __syncthreads();  // all waves done reading Q before K/V staging reuses lds

    float mrow[2][4], lsum[2][4];
    f32x4 oacc[2][8] = {};
    #pragma unroll
    for (int mf = 0; mf < 2; ++mf)
        #pragma unroll
        for (int r = 0; r < 4; ++r) { mrow[mf][r] = -1e30f; lsum[mf][r] = 0.0f; }

    const int ktend = qb * 2 + 2;
    const u16* Kg = KV + ((size_t)(b * 2048) * 512 + kvh * 128);
    const u16* Vg = KV + ((size_t)(b * 2048) * 512 + 256 + kvh * 128);
    u16* Pw = Ps + w * (32 * 72);

    for (int kt = 0; kt < ktend; ++kt) {
        __syncthreads();  // previous tile's LDS reads complete
        // stage K: linear LDS dest, inverse-swizzled global source (rule 21)
        #pragma unroll
        for (int i = 0; i < 4; ++i) {
            const int row = (w * 4 + i) * 4 + lg;
            const int srcoff = (lr * 16) ^ ((row & 7) << 4);
            gload_lds16((const char*)Kg + (size_t)(kt * 64 + row) * 1024 + srcoff,
                        (char*)Ks + (w * 4 + i) * 1024);
        }
        // stage V transposed via regs: V^T[d][k], swizzled
        {
            const u16* vrow = Vg + (size_t)(kt * 64 + l) * 512;
            #pragma unroll
            for (int c = 0; c < 4; ++c) {
                const int dbase = w * 32 + c * 8;
                s16x8 vv = *(const s16x8*)(vrow + dbase);
                #pragma unroll
                for (int j = 0; j < 8; ++j) {
                    const int d = dbase + j;
                    const int baddr = (d * 128 + l * 2) ^ ((d & 7) << 4);
                    *(u16*)((char*)Vs + baddr) = vv[j];
                }
            }
        }
        __syncthreads();  // staging complete

        // ---- QK^T: S[q][k], q-rows = A(Q), k = B(K)
        f32x4 sc[2][4] = {};
        #pragma unroll
        for (int ks = 0; ks < 4; ++ks) {
            s16x8 kf[4];
            #pragma unroll
            for (int nf = 0; nf < 4; ++nf) {
                const int row = nf * 16 + lr;
                const int boff = (row * 256 + ks * 64 + lg * 16) ^ ((row & 7) << 4);
                kf[nf] = *(const s16x8*)((const char*)Ks + boff);
            }
            #pragma unroll
            for (int mf = 0; mf < 2; ++mf)
                #pragma unroll
                for (int nf = 0; nf < 4; ++nf)
                    sc[mf][nf] = __builtin_amdgcn_mfma_f32_16x16x32_bf16(qf[mf][ks], kf[nf], sc[mf][nf], 0, 0, 0);
        }

        // ---- causal mask + online softmax (C-layout: col k=lane&15, row q=(lane>>4)*4+r)
        #pragma unroll
        for (int mf = 0; mf < 2; ++mf) {
            #pragma unroll
            for (int r = 0; r < 4; ++r) {
                const int q = q0 + w * 32 + mf * 16 + lg * 4 + r;
                float mx = -1e30f;
                #pragma unroll
                for (int nf = 0; nf < 4; ++nf) {
                    const int kpos = kt * 64 + nf * 16 + lr;
                    float s = (kpos <= q) ? sc[mf][nf][r] : -1e30f;
                    sc[mf][nf][r] = s;
                    mx = fmaxf(mx, s);
                }
                #pragma unroll
                for (int off = 1; off < 16; off <<= 1)
                    mx = fmaxf(mx, __shfl_xor(mx, off, 64));
                const float mnew = fmaxf(mrow[mf][r], mx);
                const float corr = __expf(mrow[mf][r] - mnew);
                mrow[mf][r] = mnew;
                float rs = 0.0f;
                #pragma unroll
                for (int nf = 0; nf < 4; ++nf) {
                    const float p = __expf(sc[mf][nf][r] - mnew);
                    sc[mf][nf][r] = p;
                    rs += p;
                }
                #pragma unroll
                for (int off = 1; off < 16; off <<= 1)
                    rs += __shfl_xor(rs, off, 64);
                lsum[mf][r] = lsum[mf][r] * corr + rs;
                #pragma unroll
                for (int nd = 0; nd < 8; ++nd)
                    oacc[mf][nd][r] *= corr;
            }
        }

        // ---- P (C-layout) -> per-wave LDS -> A-frag layout
        #pragma unroll
        for (int mf = 0; mf < 2; ++mf)
            #pragma unroll
            for (int nf = 0; nf < 4; ++nf)
                #pragma unroll
                for (int r = 0; r < 4; ++r)
                    Pw[(mf * 16 + lg * 4 + r) * 72 + nf * 16 + lr] = bf16_rne(sc[mf][nf][r]);

        __syncthreads();  // (safety) P writes visible before A-frag reads

        // ---- PV: O[q][d] += P[q][k] * V[k][d], B-frag from swizzled V^T
        #pragma unroll
        for (int ksb = 0; ksb < 2; ++ksb) {
            s16x8 pf[2];
            #pragma unroll
            for (int mf = 0; mf < 2; ++mf)
                pf[mf] = *(const s16x8*)(Pw + (mf * 16 + lr) * 72 + ksb * 32 + lg * 8);
            #pragma unroll
            for (int nd = 0; nd < 8; ++nd) {
                const int row = nd * 16 + lr;
                const int boff = (row * 128 + ksb * 64 + lg * 16) ^ ((row & 7) << 4);
                s16x8 vf = *(const s16x8*)((const char*)Vs + boff);
                #pragma unroll
                for (int mf = 0; mf < 2; ++mf)
                    oacc[mf][nd] = __builtin_amdgcn_mfma_f32_16x16x32_bf16(pf[mf], vf, oacc[mf][nd], 0, 0, 0);
            }
        }
    }

    // ---- epilogue: normalize, write bf16
    #pragma unroll
    for (int mf = 0; mf < 2; ++mf) {
        #pragma unroll
        for (int r = 0; r < 4; ++r) {
            const float inv = 1.0f / lsum[mf][r];
            const int q = q0 + w * 32 + mf * 16 + lg * 4 + r;
            u16* orow = O + ((size_t)(b * 2048 + q) * 2048 + h * 128);
            #pragma unroll
            for (int nd = 0; nd < 8; ++nd)
                orow[nd * 16 + lr] = bf16_rne(oacc[mf][nd][r] * inv);
        }
    }
}

// ---------------- launch ----------------
extern "C" void kernel_launch(void* const* d_in, const int* in_sizes, int n_in,
                              void* d_out, int out_size, void* d_ws, size_t ws_size,
                              hipStream_t stream) {
    const float* x    = (const float*)d_in[0];
    const float* cosb = (const float*)d_in[1];
    const float* sinb = (const float*)d_in[2];
    const float* q_w  = (const float*)d_in[3];
    const float* q_b  = (const float*)d_in[4];
    const float* kv_w = (const float*)d_in[5];
    const float* kv_b = (const float*)d_in[6];
    const float* o_w  = (const float*)d_in[7];
    float* out = (float*)d_out;

    char* p = (char*)d_ws;
    u16* x_bf   = (u16*)p; p += (size_t)4096 * 2048 * 2;
    u16* qw_bf  = (u16*)p; p += (size_t)2048 * 2048 * 2;
    u16* kvw_bf = (u16*)p; p += (size_t)512 * 2048 * 2;
    u16* ow_bf  = (u16*)p; p += (size_t)2048 * 2048 * 2;
    u16* q_bf   = (u16*)p; p += (size_t)4096 * 2048 * 2;
    u16* kv_bf  = (u16*)p; p += (size_t)4096 * 512 * 2;
    u16* at_bf  = (u16*)p; p += (size_t)4096 * 2048 * 2;
    // total 73,400,320 B of d_ws

    cvt_bf16<<<8192, 256, 0, stream>>>(x,    x_bf,   4096 * 2048 / 4);
    cvt_bf16<<<4096, 256, 0, stream>>>(q_w,  qw_bf,  2048 * 2048 / 4);
    cvt_bf16<<<1024, 256, 0, stream>>>(kv_w, kvw_bf,  512 * 2048 / 4);
    cvt_bf16<<<4096, 256, 0, stream>>>(o_w,  ow_bf,  2048 * 2048 / 4);

    gemm_bt<true, true><<<dim3(32 * 16), 256, 0, stream>>>(x_bf, qw_bf,  q_b,  q_bf,  4096, 2048, 2048);
    gemm_bt<true, true><<<dim3(32 * 4),  256, 0, stream>>>(x_bf, kvw_bf, kv_b, kv_bf, 4096,  512, 2048);

    const float qk_scale = 0.08838834764831845f;  // 1/sqrt(128), folded into Q
    rope_kernel<16, 2048><<<16384, 256, 0, stream>>>(q_bf,  cosb, sinb, qk_scale);
    rope_kernel<2,  512><<<2048,  256, 0, stream>>>(kv_bf, cosb, sinb, 1.0f);

    attn_fwd<<<dim3(16, 32), 256, 0, stream>>>(q_bf, kv_bf, at_bf);

    gemm_bt<false, false><<<dim3(32 * 16), 256, 0, stream>>>(at_bf, ow_bf, nullptr, out, 4096, 2048, 2048);
}

// Round 2
// 252.664 us; speedup vs baseline: 1.3531x; 1.3531x over previous
//
#include <hip/hip_runtime.h>

typedef unsigned short u16;
typedef unsigned long long u64;
typedef __attribute__((ext_vector_type(4))) float f32x4;
typedef __attribute__((ext_vector_type(8))) short s16x8;

#define DEV __device__ __forceinline__

DEV u16 bf16_rne(float f) {
    unsigned u = __builtin_bit_cast(unsigned, f);
    u += 0x7fffu + ((u >> 16) & 1u);
    return (u16)(u >> 16);
}
DEV float bf2f(u16 h) {
    unsigned u = ((unsigned)h) << 16;
    return __builtin_bit_cast(float, u);
}
DEV void gload_lds16(const void* g, void* l) {
    __builtin_amdgcn_global_load_lds((const __attribute__((address_space(1))) void*)g,
                                     (__attribute__((address_space(3))) void*)l, 16, 0, 0);
}

// ---------------- f32 -> bf16 convert (vectorized x4) ----------------
__global__ __launch_bounds__(256)
void cvt_bf16(const float* __restrict__ in, u16* __restrict__ out, int n4) {
    int i = blockIdx.x * 256 + threadIdx.x;
    if (i >= n4) return;
    f32x4 v = ((const f32x4*)in)[i];
    u64 o =  (u64)bf16_rne(v[0])
          | ((u64)bf16_rne(v[1]) << 16)
          | ((u64)bf16_rne(v[2]) << 32)
          | ((u64)bf16_rne(v[3]) << 48);
    ((u64*)out)[i] = o;
}

// ---------------- bf16 GEMM, C = A(MxK) * B(NxK)^T + bias ----------------
// 128x128 tile, BK=64, 256 threads (4 waves, 2x2), mfma 16x16x32 bf16.
// MODE 0: bf16 out + bias. MODE 1: f32 out, no bias.
// MODE 2: KV split: cols 0..255 -> K rows [b][kvh][s][128] (Cout), cols 256..511 ->
//         V^T [b][kvh][d][s] (Cout2). bias applied.
template<int MODE>
__global__ __launch_bounds__(256)
void gemm_bt(const u16* __restrict__ A, const u16* __restrict__ B,
             const float* __restrict__ bias, void* __restrict__ Cout,
             void* __restrict__ Cout2, int M, int N, int K) {
    __shared__ u16 As[128 * 64];
    __shared__ u16 Bs[128 * 64];
    const int tid = threadIdx.x;
    const int w = tid >> 6, l = tid & 63;
    const int nbn = N >> 7;
    const int bm = blockIdx.x / nbn;
    const int bn = blockIdx.x % nbn;
    const int wr = w >> 1, wc = w & 1;
    const int lr = l & 15, lg = l >> 4;
    const int rowsel = l >> 3, chunk = l & 7;

    f32x4 acc[4][4] = {};

    const u16* Abase = A + (size_t)(bm * 128 + w * 32) * K;
    const u16* Bbase = B + (size_t)(bn * 128 + w * 32) * K;
    u16* AsW = As + (w * 32) * 64;
    u16* BsW = Bs + (w * 32) * 64;

    for (int k0 = 0; k0 < K; k0 += 64) {
        __syncthreads();
        #pragma unroll
        for (int i = 0; i < 4; ++i) {
            gload_lds16(Abase + (size_t)(i * 8 + rowsel) * K + k0 + chunk * 8, AsW + i * 8 * 64);
            gload_lds16(Bbase + (size_t)(i * 8 + rowsel) * K + k0 + chunk * 8, BsW + i * 8 * 64);
        }
        __syncthreads();
        #pragma unroll
        for (int ks = 0; ks < 2; ++ks) {
            s16x8 af[4], bfr[4];
            #pragma unroll
            for (int mi = 0; mi < 4; ++mi)
                af[mi] = *(const s16x8*)(As + (wr * 64 + mi * 16 + lr) * 64 + ks * 32 + lg * 8);
            #pragma unroll
            for (int ni = 0; ni < 4; ++ni)
                bfr[ni] = *(const s16x8*)(Bs + (wc * 64 + ni * 16 + lr) * 64 + ks * 32 + lg * 8);
            #pragma unroll
            for (int mi = 0; mi < 4; ++mi)
                #pragma unroll
                for (int ni = 0; ni < 4; ++ni)
                    acc[mi][ni] = __builtin_amdgcn_mfma_f32_16x16x32_bf16(af[mi], bfr[ni], acc[mi][ni], 0, 0, 0);
        }
    }

    const int row0 = bm * 128 + wr * 64;
    const int col0 = bn * 128 + wc * 64;
    #pragma unroll
    for (int ni = 0; ni < 4; ++ni) {
        const int col = col0 + ni * 16 + lr;
        const float bv = (MODE == 1) ? 0.0f : bias[col];
        #pragma unroll
        for (int mi = 0; mi < 4; ++mi) {
            if (MODE == 2) {
                const int bb = row0 >> 11;
                const int s = (row0 & 2047) + mi * 16 + lg * 4;
                float v0 = acc[mi][ni][0] + bv, v1 = acc[mi][ni][1] + bv;
                float v2 = acc[mi][ni][2] + bv, v3 = acc[mi][ni][3] + bv;
                if (col < 256) {
                    const int kvh = col >> 7, d = col & 127;
                    u16* kp = (u16*)Cout + ((size_t)(bb * 2 + kvh) * 2048 + s) * 128 + d;
                    kp[0]   = bf16_rne(v0);
                    kp[128] = bf16_rne(v1);
                    kp[256] = bf16_rne(v2);
                    kp[384] = bf16_rne(v3);
                } else {
                    const int kvh = (col - 256) >> 7, d = (col - 256) & 127;
                    u64 pk =  (u64)bf16_rne(v0)
                           | ((u64)bf16_rne(v1) << 16)
                           | ((u64)bf16_rne(v2) << 32)
                           | ((u64)bf16_rne(v3) << 48);
                    *(u64*)((u16*)Cout2 + ((size_t)(bb * 2 + kvh) * 128 + d) * 2048 + s) = pk;
                }
            } else {
                #pragma unroll
                for (int r = 0; r < 4; ++r) {
                    const int row = row0 + mi * 16 + lg * 4 + r;
                    const float v = acc[mi][ni][r] + bv;
                    if (MODE == 0) ((u16*)Cout)[(size_t)row * N + col] = bf16_rne(v);
                    else           ((float*)Cout)[(size_t)row * N + col] = v;
                }
            }
        }
    }
}

// ---------------- RoPE in-place on bf16, pairs (d, d+64) per 128-head ----------------
template<int NHEADS, int ROWSTRIDE>
__global__ __launch_bounds__(256)
void rope_kernel(u16* __restrict__ t, const float* __restrict__ cosb,
                 const float* __restrict__ sinb, float scale) {
    const int i = blockIdx.x * 256 + threadIdx.x;
    const int d = i & 63;
    const int h = (i >> 6) % NHEADS;
    const int bs = (i >> 6) / NHEADS;
    const int srow = bs & 2047;
    const size_t base = (size_t)bs * ROWSTRIDE + h * 128;
    const float c0 = cosb[srow * 128 + d],      s0 = sinb[srow * 128 + d];
    const float c1 = cosb[srow * 128 + d + 64], s1 = sinb[srow * 128 + d + 64];
    const float t0 = bf2f(t[base + d]);
    const float t1 = bf2f(t[base + d + 64]);
    t[base + d]      = bf16_rne((t0 * c0 - t1 * s0) * scale);
    t[base + d + 64] = bf16_rne((t1 * c1 + t0 * s1) * scale);
}

// ---------------- causal GQA flash attention (swapped-QK, paired tiles) ----------------
// grid (16, 32): x = tile-pair index pi (tiles pi and 31-pi, 64 q-rows each),
// y = b*16 + h. 256 threads = 4 waves; wave w owns q rows tile*64 + w*16 + [0,16).
__global__ __launch_bounds__(256, 2)
void attn_fwd(const u16* __restrict__ Q, const u16* __restrict__ Kb,
              const u16* __restrict__ VTb, u16* __restrict__ O) {
    __shared__ u16 lds[64 * 128 + 128 * 64 + 4 * 16 * 72];  // K 16KB + V^T 16KB + P 9KB
    u16* Ks = lds;                  // [64 k][128 d], XOR-swizzled
    u16* Vs = lds + 64 * 128;       // [128 d][64 k] (V^T), XOR-swizzled
    u16* Ps = lds + 64 * 128 + 128 * 64;

    const int tid = threadIdx.x, w = tid >> 6, l = tid & 63;
    const int lr = l & 15, lg = l >> 4;
    const int pi = blockIdx.x;
    const int bh = blockIdx.y;
    const int b = bh >> 4, h = bh & 15;
    const int kvh = h >> 3;
    const u16* Kg = Kb + (size_t)(b * 2 + kvh) * 2048 * 128;
    const u16* Vg = VTb + (size_t)(b * 2 + kvh) * 128 * 2048;
    u16* Pw = Ps + w * (16 * 72);

    #pragma unroll 1
    for (int t = 0; t < 2; ++t) {
        const int tile = t ? (31 - pi) : pi;
        const int qrow = tile * 64 + w * 16 + lr;   // this lane's q column
        // Q fragments straight from global (L2-resident)
        s16x8 qf[4];
        {
            const u16* Qrow = Q + ((size_t)(b * 2048 + qrow) * 2048 + h * 128);
            #pragma unroll
            for (int ks = 0; ks < 4; ++ks)
                qf[ks] = *(const s16x8*)(Qrow + ks * 32 + lg * 8);
        }

        float m = -1e30f, lsum = 0.0f;
        f32x4 oacc[8] = {};

        const int ktend = tile + 1;
        for (int kt = 0; kt < ktend; ++kt) {
            __syncthreads();  // previous iteration's LDS reads complete
            // stage K [64][128]: linear LDS dest, inverse-swizzled global source
            #pragma unroll
            for (int i = 0; i < 4; ++i) {
                const int row = (w * 4 + i) * 4 + lg;
                const int srcoff = (lr * 16) ^ ((row & 7) << 4);
                gload_lds16((const char*)Kg + (size_t)(kt * 64 + row) * 256 + srcoff,
                            (char*)Ks + (w * 4 + i) * 1024);
            }
            // stage V^T [128][64]
            #pragma unroll
            for (int i = 0; i < 4; ++i) {
                const int d = (w * 4 + i) * 8 + (l >> 3);
                const int srcoff = ((l & 7) * 16) ^ ((d & 7) << 4);
                gload_lds16((const char*)Vg + (size_t)d * 4096 + (size_t)kt * 128 + srcoff,
                            (char*)Vs + (w * 4 + i) * 1024);
            }
            __syncthreads();  // staging complete

            // ---- swapped QK^T: sc[kf] rows k = kf*16+lg*4+r, col q = lr
            f32x4 sc[4] = {};
            #pragma unroll
            for (int ks = 0; ks < 4; ++ks) {
                #pragma unroll
                for (int kf = 0; kf < 4; ++kf) {
                    const int row = kf * 16 + lr;
                    const int boff = (row * 256 + ks * 64 + lg * 16) ^ ((row & 7) << 4);
                    s16x8 kfr = *(const s16x8*)((const char*)Ks + boff);
                    sc[kf] = __builtin_amdgcn_mfma_f32_16x16x32_bf16(kfr, qf[ks], sc[kf], 0, 0, 0);
                }
            }

            // ---- causal mask + online softmax (k lane-local: 2+2 shfls total)
            float mx = m;
            #pragma unroll
            for (int kf = 0; kf < 4; ++kf)
                #pragma unroll
                for (int r = 0; r < 4; ++r) {
                    const int kpos = kt * 64 + kf * 16 + lg * 4 + r;
                    float s = (kpos <= qrow) ? sc[kf][r] : -1e30f;
                    sc[kf][r] = s;
                    mx = fmaxf(mx, s);
                }
            mx = fmaxf(mx, __shfl_xor(mx, 16, 64));
            mx = fmaxf(mx, __shfl_xor(mx, 32, 64));
            const float corr = __expf(m - mx);
            m = mx;
            float rs = 0.0f;
            #pragma unroll
            for (int kf = 0; kf < 4; ++kf)
                #pragma unroll
                for (int r = 0; r < 4; ++r) {
                    const float p = __expf(sc[kf][r] - mx);
                    sc[kf][r] = p;
                    rs += p;
                }
            rs += __shfl_xor(rs, 16, 64);
            rs += __shfl_xor(rs, 32, 64);
            lsum = lsum * corr + rs;
            // rescale O: need corr of q-row lg*4+r (lives in lane lr = lg*4+r)
            float corrq[4];
            #pragma unroll
            for (int r = 0; r < 4; ++r)
                corrq[r] = __shfl(corr, lg * 4 + r, 64);
            #pragma unroll
            for (int nd = 0; nd < 8; ++nd)
                #pragma unroll
                for (int r = 0; r < 4; ++r)
                    oacc[nd][r] *= corrq[r];

            // ---- P -> wave-private padded LDS [16][72] (no barrier needed)
            #pragma unroll
            for (int kf = 0; kf < 4; ++kf) {
                u64 pkd =  (u64)bf16_rne(sc[kf][0])
                        | ((u64)bf16_rne(sc[kf][1]) << 16)
                        | ((u64)bf16_rne(sc[kf][2]) << 32)
                        | ((u64)bf16_rne(sc[kf][3]) << 48);
                *(u64*)((char*)Pw + lr * 144 + kf * 32 + lg * 8) = pkd;
            }
            s16x8 pf[2];
            #pragma unroll
            for (int ksb = 0; ksb < 2; ++ksb)
                pf[ksb] = *(const s16x8*)((char*)Pw + lr * 144 + ksb * 64 + lg * 16);

            // ---- PV: oacc[nd] rows q = lg*4+r, col d = nd*16+lr
            #pragma unroll
            for (int ksb = 0; ksb < 2; ++ksb)
                #pragma unroll
                for (int nd = 0; nd < 8; ++nd) {
                    const int row = nd * 16 + lr;
                    const int boff = (row * 128 + ksb * 64 + lg * 16) ^ ((row & 7) << 4);
                    s16x8 vf = *(const s16x8*)((const char*)Vs + boff);
                    oacc[nd] = __builtin_amdgcn_mfma_f32_16x16x32_bf16(pf[ksb], vf, oacc[nd], 0, 0, 0);
                }
        }

        // ---- epilogue: normalize (inv lives in lane lr = q-row), write bf16
        const float inv = 1.0f / lsum;
        float invq[4];
        #pragma unroll
        for (int r = 0; r < 4; ++r)
            invq[r] = __shfl(inv, lg * 4 + r, 64);
        #pragma unroll
        for (int r = 0; r < 4; ++r) {
            const int q = tile * 64 + w * 16 + lg * 4 + r;
            u16* orow = O + ((size_t)(b * 2048 + q) * 2048 + h * 128);
            #pragma unroll
            for (int nd = 0; nd < 8; ++nd)
                orow[nd * 16 + lr] = bf16_rne(oacc[nd][r] * invq[r]);
        }
    }
}

// ---------------- launch ----------------
extern "C" void kernel_launch(void* const* d_in, const int* in_sizes, int n_in,
                              void* d_out, int out_size, void* d_ws, size_t ws_size,
                              hipStream_t stream) {
    const float* x    = (const float*)d_in[0];
    const float* cosb = (const float*)d_in[1];
    const float* sinb = (const float*)d_in[2];
    const float* q_w  = (const float*)d_in[3];
    const float* q_b  = (const float*)d_in[4];
    const float* kv_w = (const float*)d_in[5];
    const float* kv_b = (const float*)d_in[6];
    const float* o_w  = (const float*)d_in[7];
    float* out = (float*)d_out;

    char* p = (char*)d_ws;
    u16* x_bf   = (u16*)p; p += (size_t)4096 * 2048 * 2;
    u16* qw_bf  = (u16*)p; p += (size_t)2048 * 2048 * 2;
    u16* kvw_bf = (u16*)p; p += (size_t)512 * 2048 * 2;
    u16* ow_bf  = (u16*)p; p += (size_t)2048 * 2048 * 2;
    u16* q_bf   = (u16*)p; p += (size_t)4096 * 2048 * 2;
    u16* k_bf   = (u16*)p; p += (size_t)4 * 2048 * 128 * 2;   // [b][kvh][s][d]
    u16* vt_bf  = (u16*)p; p += (size_t)4 * 128 * 2048 * 2;   // [b][kvh][d][s]
    u16* at_bf  = (u16*)p; p += (size_t)4096 * 2048 * 2;

    cvt_bf16<<<8192, 256, 0, stream>>>(x,    x_bf,   4096 * 2048 / 4);
    cvt_bf16<<<4096, 256, 0, stream>>>(q_w,  qw_bf,  2048 * 2048 / 4);
    cvt_bf16<<<1024, 256, 0, stream>>>(kv_w, kvw_bf,  512 * 2048 / 4);
    cvt_bf16<<<4096, 256, 0, stream>>>(o_w,  ow_bf,  2048 * 2048 / 4);

    gemm_bt<0><<<dim3(32 * 16), 256, 0, stream>>>(x_bf, qw_bf,  q_b,  q_bf, nullptr, 4096, 2048, 2048);
    gemm_bt<2><<<dim3(32 * 4),  256, 0, stream>>>(x_bf, kvw_bf, kv_b, k_bf, vt_bf,   4096,  512, 2048);

    const float qk_scale = 0.08838834764831845f;  // 1/sqrt(128), folded into Q
    rope_kernel<16, 2048><<<16384, 256, 0, stream>>>(q_bf, cosb, sinb, qk_scale);
    rope_kernel<1, 128><<<2048, 256, 0, stream>>>(k_bf, cosb, sinb, 1.0f);

    attn_fwd<<<dim3(16, 32), 256, 0, stream>>>(q_bf, k_bf, vt_bf, at_bf);

    gemm_bt<1><<<dim3(32 * 16), 256, 0, stream>>>(at_bf, ow_bf, nullptr, out, nullptr, 4096, 2048, 2048);
}